// Round 2
// baseline (235.185 us; speedup 1.0000x reference)
//
#include <hip/hip_runtime.h>

#define BN 256   // batches
#define NN 256   // matrix dim
#define WL 8     // walk length

typedef unsigned short u16;
typedef __attribute__((ext_vector_type(8))) short short8;
typedef __attribute__((ext_vector_type(4))) float f32x4;

__device__ inline u16 f2bf(float x) {
  union { float f; unsigned u; } v; v.f = x;
  unsigned r = v.u + 0x7fffu + ((v.u >> 16) & 1u);   // RNE
  return (u16)(r >> 16);
}
__device__ inline float bf2f(u16 h) {
  union { unsigned u; float f; } v; v.u = ((unsigned)h) << 16;
  return v.f;
}

// ---- K1: P = rownorm(threshold(A)) [f32 in, bf16 out]; out cols 0,1 (f32) --
// one wave per row; 4 waves per block
__global__ __launch_bounds__(256) void k_prep(const float* __restrict__ A,
                                              u16* __restrict__ P,
                                              float* __restrict__ out) {
  int gw = blockIdx.x * 4 + (threadIdx.x >> 6);   // global row id in [0, BN*NN)
  int l  = threadIdx.x & 63;

  float4 v = *(const float4*)(A + (size_t)gw * NN + l * 4);
  float t0 = v.x > 0.3f ? v.x : 0.0f;
  float t1 = v.y > 0.3f ? v.y : 0.0f;
  float t2 = v.z > 0.3f ? v.z : 0.0f;
  float t3 = v.w > 0.3f ? v.w : 0.0f;
  float s = (t0 + t1) + (t2 + t3);
  #pragma unroll
  for (int off = 32; off; off >>= 1) s += __shfl_xor(s, off);
  float dinv = s > 0.0f ? 1.0f / s : 0.0f;
  float p0 = t0 * dinv, p1 = t1 * dinv, p2 = t2 * dinv, p3 = t3 * dinv;

  uint2 pw;
  pw.x = (unsigned)f2bf(p0) | ((unsigned)f2bf(p1) << 16);
  pw.y = (unsigned)f2bf(p2) | ((unsigned)f2bf(p3) << 16);
  *(uint2*)(P + (size_t)gw * NN + l * 4) = pw;

  int i = gw & (NN - 1);            // row index within batch (wave-uniform)
  int sel = i & 3;                  // wave-uniform select, no scratch array
  float x = sel == 0 ? p0 : sel == 1 ? p1 : sel == 2 ? p2 : p3;
  float dval = __shfl(x, i >> 2);
  if (l == 0) {
    out[(size_t)gw * WL + 0] = 1.0f;
    out[(size_t)gw * WL + 1] = dval;
  }
}

// ---- K2: PT = P^T per batch (64x64 LDS tiles, bf16) ------------------------
__global__ __launch_bounds__(256) void k_transpose(const u16* __restrict__ P,
                                                   u16* __restrict__ PT) {
  __shared__ u16 tile[64][72];
  int b  = blockIdx.y;
  int tr = (blockIdx.x >> 2) * 64, tc = (blockIdx.x & 3) * 64;
  const u16* Pb = P + (size_t)b * NN * NN;
  u16* PTb      = PT + (size_t)b * NN * NN;
  int t = threadIdx.x;
  int r = t >> 2, c0 = (t & 3) * 16;

  const uint4* src = (const uint4*)(Pb + (size_t)(tr + r) * NN + tc + c0);
  uint4 x0 = src[0], x1 = src[1];
  *(uint4*)&tile[r][c0]     = x0;
  *(uint4*)&tile[r][c0 + 8] = x1;
  __syncthreads();

  int c = t >> 2, r0 = (t & 3) * 16;
  unsigned wbuf[8];
  #pragma unroll
  for (int k = 0; k < 8; k++)
    wbuf[k] = (unsigned)tile[r0 + 2 * k][c] | ((unsigned)tile[r0 + 2 * k + 1][c] << 16);
  uint4 y0 = {wbuf[0], wbuf[1], wbuf[2], wbuf[3]};
  uint4 y1 = {wbuf[4], wbuf[5], wbuf[6], wbuf[7]};
  uint4* dst = (uint4*)(PTb + (size_t)(tc + c) * NN + tr + r0);
  dst[0] = y0; dst[1] = y1;
}

// ---- K3: C = A * B (BT = B^T given), fused diag -> out[:, g] (f32) ---------
// 128x128 tile, 4 waves, BK=32, global_load_lds staging, m97-style.
#define GLDS(gp, lp) \
  __builtin_amdgcn_global_load_lds((const __attribute__((address_space(1))) void*)(gp), \
                                   (__attribute__((address_space(3))) void*)(lp), 16, 0, 0)

__global__ __launch_bounds__(256) void k_gemm(const u16* __restrict__ Aall,
                                              const u16* __restrict__ BTall,
                                              u16* __restrict__ Call,
                                              float* __restrict__ out,
                                              int g) {
  __shared__ u16 As[128 * 32];   // 8 KB, [row][k]
  __shared__ u16 Bs[128 * 32];   // 8 KB, [col][k]  (BT tile)
  int b    = blockIdx.y;
  int tile = blockIdx.x;                       // 0..3
  int bRow = (tile >> 1) * 128, bCol = (tile & 1) * 128;
  const u16* Ab  = Aall  + (size_t)b * NN * NN;
  const u16* BTb = BTall + (size_t)b * NN * NN;

  int t = threadIdx.x;
  int w = t >> 6, l = t & 63;
  int quad = l >> 4, l16 = l & 15;
  int wm = (w >> 1) * 64, wn = (w & 1) * 64;
  int srow  = t >> 2;                          // staging row 0..63
  int sbyte = (t & 3) * 16;

  f32x4 acc[4][4];
  #pragma unroll
  for (int i = 0; i < 4; i++)
    #pragma unroll
    for (int j = 0; j < 4; j++)
      acc[i][j] = (f32x4){0.f, 0.f, 0.f, 0.f};

  for (int k0 = 0; k0 < NN; k0 += 32) {
    __syncthreads();
    const char* ga = (const char*)(Ab  + (size_t)(bRow + srow) * NN + k0) + sbyte;
    const char* gb = (const char*)(BTb + (size_t)(bCol + srow) * NN + k0) + sbyte;
    char* la = (char*)As + w * 1024;
    char* lb = (char*)Bs + w * 1024;
    GLDS(ga,                la);
    GLDS(ga + 64 * NN * 2,  la + 4096);
    GLDS(gb,                lb);
    GLDS(gb + 64 * NN * 2,  lb + 4096);
    __syncthreads();

    short8 af[4], bf[4];
    #pragma unroll
    for (int mt = 0; mt < 4; mt++)
      af[mt] = *(const short8*)(As + (wm + mt * 16 + l16) * 32 + quad * 8);
    #pragma unroll
    for (int nt = 0; nt < 4; nt++)
      bf[nt] = *(const short8*)(Bs + (wn + nt * 16 + l16) * 32 + quad * 8);
    #pragma unroll
    for (int mt = 0; mt < 4; mt++)
      #pragma unroll
      for (int nt = 0; nt < 4; nt++)
        acc[mt][nt] = __builtin_amdgcn_mfma_f32_16x16x32_bf16(af[mt], bf[nt], acc[mt][nt], 0, 0, 0);
  }

  u16* Cb = Call + (size_t)b * NN * NN;
  #pragma unroll
  for (int mt = 0; mt < 4; mt++) {
    int row0 = bRow + wm + mt * 16 + quad * 4;
    #pragma unroll
    for (int nt = 0; nt < 4; nt++) {
      int col = bCol + wn + nt * 16 + l16;
      #pragma unroll
      for (int r = 0; r < 4; r++)
        Cb[(size_t)(row0 + r) * NN + col] = f2bf(acc[mt][nt][r]);
    }
  }
  // fused diag -> out[b][d][g], f32 (C layout: col=l16, row=quad*4+r)
  if (bRow == bCol && wm == wn) {
    #pragma unroll
    for (int mt = 0; mt < 4; mt++) {
      #pragma unroll
      for (int r = 0; r < 4; r++) {
        if (l16 == quad * 4 + r) {
          int d = bRow + wm + mt * 16 + l16;
          out[((size_t)b * NN + d) * WL + g] = acc[mt][mt][r];
        }
      }
    }
  }
}

// ---- K4: diag(Xa*Y), diag(Xb*Y), diag(Xc*Y) via row-dots against YT --------
// diag(X*Y)_i = sum_j X[i][j] * YT[i][j]; one wave per row.
__global__ __launch_bounds__(256) void k_rowdot(const u16* __restrict__ Xa,
                                                const u16* __restrict__ Xb,
                                                const u16* __restrict__ Xc,
                                                const u16* __restrict__ YT,
                                                float* __restrict__ out) {
  int gw = blockIdx.x * 4 + (threadIdx.x >> 6);
  int l  = threadIdx.x & 63;
  size_t off = (size_t)gw * NN + l * 4;

  uint2 ya = *(const uint2*)(YT + off);
  uint2 xa = *(const uint2*)(Xa + off);
  uint2 xb = *(const uint2*)(Xb + off);
  uint2 xc = *(const uint2*)(Xc + off);
  float y0 = bf2f((u16)(ya.x & 0xffff)), y1 = bf2f((u16)(ya.x >> 16));
  float y2 = bf2f((u16)(ya.y & 0xffff)), y3 = bf2f((u16)(ya.y >> 16));

  float sa = bf2f((u16)(xa.x & 0xffff)) * y0 + bf2f((u16)(xa.x >> 16)) * y1
           + bf2f((u16)(xa.y & 0xffff)) * y2 + bf2f((u16)(xa.y >> 16)) * y3;
  float sb = bf2f((u16)(xb.x & 0xffff)) * y0 + bf2f((u16)(xb.x >> 16)) * y1
           + bf2f((u16)(xb.y & 0xffff)) * y2 + bf2f((u16)(xb.y >> 16)) * y3;
  float sc = bf2f((u16)(xc.x & 0xffff)) * y0 + bf2f((u16)(xc.x >> 16)) * y1
           + bf2f((u16)(xc.y & 0xffff)) * y2 + bf2f((u16)(xc.y >> 16)) * y3;
  #pragma unroll
  for (int o = 32; o; o >>= 1) {
    sa += __shfl_xor(sa, o);
    sb += __shfl_xor(sb, o);
    sc += __shfl_xor(sc, o);
  }
  if (l == 0) {
    size_t o = (size_t)gw * WL;
    out[o + 5] = sa;   // diag(P^5) = rowdot(P^2, P^3T)
    out[o + 6] = sb;   // diag(P^6) = rowdot(P^3, P^3T)
    out[o + 7] = sc;   // diag(P^7) = rowdot(P^4, P^3T)
  }
}

extern "C" void kernel_launch(void* const* d_in, const int* in_sizes, int n_in,
                              void* d_out, int out_size, void* d_ws, size_t ws_size,
                              hipStream_t stream) {
  const float* A = (const float*)d_in[0];
  float* out = (float*)d_out;
  const size_t M3 = (size_t)BN * NN * NN;   // 16.78M elems, 32 MB bf16 each
  u16* b0 = (u16*)d_ws;      // P, later P^4
  u16* b1 = b0 + M3;         // P^T, later P^3T
  u16* b2 = b1 + M3;         // P^2
  u16* b3 = b2 + M3;         // P^3   (128 MB d_ws total)

  k_prep<<<BN * NN / 4, 256, 0, stream>>>(A, b0, out);              // P, cols 0,1
  k_transpose<<<dim3(16, BN), 256, 0, stream>>>(b0, b1);            // PT
  k_gemm<<<dim3(4, BN), 256, 0, stream>>>(b0, b1, b2, out, 2);      // P2 = P*P
  k_gemm<<<dim3(4, BN), 256, 0, stream>>>(b2, b1, b3, out, 3);      // P3 = P2*P
  k_gemm<<<dim3(4, BN), 256, 0, stream>>>(b3, b1, b0, out, 4);      // P4 = P3*P
  k_transpose<<<dim3(16, BN), 256, 0, stream>>>(b3, b1);            // P3T
  k_rowdot<<<BN * NN / 4, 256, 0, stream>>>(b2, b3, b0, b1, out);   // cols 5,6,7
}

// Round 3
// 229.546 us; speedup vs baseline: 1.0246x; 1.0246x over previous
//
#include <hip/hip_runtime.h>

#define BN 256   // batches
#define NN 256   // matrix dim
#define WL 8     // walk length

typedef unsigned short u16;
typedef __attribute__((ext_vector_type(8))) short short8;
typedef __attribute__((ext_vector_type(4))) float f32x4;

__device__ inline u16 f2bf(float x) {
  union { float f; unsigned u; } v; v.f = x;
  unsigned r = v.u + 0x7fffu + ((v.u >> 16) & 1u);   // RNE
  return (u16)(r >> 16);
}
__device__ inline float bf2f(u16 h) {
  union { unsigned u; float f; } v; v.u = ((unsigned)h) << 16;
  return v.f;
}

// ---- K1: P = rownorm(threshold(A)) [f32 in, bf16 out]; out cols 0,1 (f32) --
__global__ __launch_bounds__(256) void k_prep(const float* __restrict__ A,
                                              u16* __restrict__ P,
                                              float* __restrict__ out) {
  int gw = blockIdx.x * 4 + (threadIdx.x >> 6);   // global row id
  int l  = threadIdx.x & 63;

  float4 v = *(const float4*)(A + (size_t)gw * NN + l * 4);
  float t0 = v.x > 0.3f ? v.x : 0.0f;
  float t1 = v.y > 0.3f ? v.y : 0.0f;
  float t2 = v.z > 0.3f ? v.z : 0.0f;
  float t3 = v.w > 0.3f ? v.w : 0.0f;
  float s = (t0 + t1) + (t2 + t3);
  #pragma unroll
  for (int off = 32; off; off >>= 1) s += __shfl_xor(s, off);
  float dinv = s > 0.0f ? 1.0f / s : 0.0f;
  float p0 = t0 * dinv, p1 = t1 * dinv, p2 = t2 * dinv, p3 = t3 * dinv;

  uint2 pw;
  pw.x = (unsigned)f2bf(p0) | ((unsigned)f2bf(p1) << 16);
  pw.y = (unsigned)f2bf(p2) | ((unsigned)f2bf(p3) << 16);
  *(uint2*)(P + (size_t)gw * NN + l * 4) = pw;

  int i = gw & (NN - 1);
  int sel = i & 3;
  float x = sel == 0 ? p0 : sel == 1 ? p1 : sel == 2 ? p2 : p3;
  float dval = __shfl(x, i >> 2);
  if (l == 0) {
    out[(size_t)gw * WL + 0] = 1.0f;
    out[(size_t)gw * WL + 1] = dval;
  }
}

// ---- K2: PT = P^T per batch (64x64 LDS tiles, bf16) ------------------------
__global__ __launch_bounds__(256) void k_transpose(const u16* __restrict__ P,
                                                   u16* __restrict__ PT) {
  __shared__ u16 tile[64][72];
  int b  = blockIdx.y;
  int tr = (blockIdx.x >> 2) * 64, tc = (blockIdx.x & 3) * 64;
  const u16* Pb = P + (size_t)b * NN * NN;
  u16* PTb      = PT + (size_t)b * NN * NN;
  int t = threadIdx.x;
  int r = t >> 2, c0 = (t & 3) * 16;

  const uint4* src = (const uint4*)(Pb + (size_t)(tr + r) * NN + tc + c0);
  uint4 x0 = src[0], x1 = src[1];
  *(uint4*)&tile[r][c0]     = x0;
  *(uint4*)&tile[r][c0 + 8] = x1;
  __syncthreads();

  int c = t >> 2, r0 = (t & 3) * 16;
  unsigned wbuf[8];
  #pragma unroll
  for (int k = 0; k < 8; k++)
    wbuf[k] = (unsigned)tile[r0 + 2 * k][c] | ((unsigned)tile[r0 + 2 * k + 1][c] << 16);
  uint4 y0 = {wbuf[0], wbuf[1], wbuf[2], wbuf[3]};
  uint4 y1 = {wbuf[4], wbuf[5], wbuf[6], wbuf[7]};
  uint4* dst = (uint4*)(PTb + (size_t)(tc + c) * NN + tr + r0);
  dst[0] = y0; dst[1] = y1;
}

// ---- K3: C = A*B (BT given). Double-buffered LDS, 1 barrier/iter, ----------
// prefetch-after-barrier; coalesced epilogue via LDS bounce; optional
// transposed output (writeT) and fused diag -> out[:, g].
#define GLDS(gp, lp) \
  __builtin_amdgcn_global_load_lds((const __attribute__((address_space(1))) void*)(gp), \
                                   (__attribute__((address_space(3))) void*)(lp), 16, 0, 0)

__global__ __launch_bounds__(256) void k_gemm(const u16* __restrict__ Aall,
                                              const u16* __restrict__ BTall,
                                              u16* __restrict__ Call,   // normal C (if writeC)
                                              u16* __restrict__ CTall,  // transposed C (if writeT)
                                              float* __restrict__ out,
                                              int g, int writeC, int writeT) {
  // S layout (bytes): buf b at b*16384: [A-tile 8192 | B-tile 8192]
  __shared__ u16 S[16384];   // 32 KB
  int b    = blockIdx.y;
  int tile = blockIdx.x;
  int bRow = (tile >> 1) * 128, bCol = (tile & 1) * 128;
  const u16* Ab  = Aall  + (size_t)b * NN * NN;
  const u16* BTb = BTall + (size_t)b * NN * NN;

  int t = threadIdx.x;
  int w = t >> 6, l = t & 63;
  int quad = l >> 4, l16 = l & 15;
  int wm = (w >> 1) * 64, wn = (w & 1) * 64;
  int srow  = t >> 2;
  int sbyte = (t & 3) * 16;

  f32x4 acc[4][4];
  #pragma unroll
  for (int i = 0; i < 4; i++)
    #pragma unroll
    for (int j = 0; j < 4; j++)
      acc[i][j] = (f32x4){0.f, 0.f, 0.f, 0.f};

  const char* gaBase = (const char*)(Ab  + (size_t)(bRow + srow) * NN) + sbyte;
  const char* gbBase = (const char*)(BTb + (size_t)(bCol + srow) * NN) + sbyte;

  // prologue: stage tile 0 into buf 0
  {
    char* la = (char*)S + w * 1024;
    char* lb = la + 8192;
    GLDS(gaBase,                la);
    GLDS(gaBase + 64 * NN * 2,  la + 4096);
    GLDS(gbBase,                lb);
    GLDS(gbBase + 64 * NN * 2,  lb + 4096);
  }

  for (int i = 0; i < 8; i++) {
    __syncthreads();   // drains vmcnt -> buf[i&1] staged; buf[(i+1)&1] free
    if (i < 7) {       // prefetch next tile; overlaps with MFMA below
      int koff = (i + 1) * 64;   // bytes: 32 elems * 2B
      char* la = (char*)S + ((i + 1) & 1) * 16384 + w * 1024;
      char* lb = la + 8192;
      GLDS(gaBase + koff,                la);
      GLDS(gaBase + koff + 64 * NN * 2,  la + 4096);
      GLDS(gbBase + koff,                lb);
      GLDS(gbBase + koff + 64 * NN * 2,  lb + 4096);
    }
    const u16* Asb = (const u16*)((const char*)S + (i & 1) * 16384);
    const u16* Bsb = Asb + 4096;

    short8 af[4], bf[4];
    #pragma unroll
    for (int mt = 0; mt < 4; mt++)
      af[mt] = *(const short8*)(Asb + (wm + mt * 16 + l16) * 32 + quad * 8);
    #pragma unroll
    for (int nt = 0; nt < 4; nt++)
      bf[nt] = *(const short8*)(Bsb + (wn + nt * 16 + l16) * 32 + quad * 8);
    #pragma unroll
    for (int mt = 0; mt < 4; mt++)
      #pragma unroll
      for (int nt = 0; nt < 4; nt++)
        acc[mt][nt] = __builtin_amdgcn_mfma_f32_16x16x32_bf16(af[mt], bf[nt], acc[mt][nt], 0, 0, 0);
  }

  // fused diag -> out[b][d][g] (C layout: col=l16, row=quad*4+r)
  if (bRow == bCol && wm == wn) {
    #pragma unroll
    for (int mt = 0; mt < 4; mt++) {
      #pragma unroll
      for (int r = 0; r < 4; r++) {
        if (l16 == quad * 4 + r) {
          int d = bRow + wm + mt * 16 + l16;
          out[((size_t)b * NN + d) * WL + g] = acc[mt][mt][r];
        }
      }
    }
  }

  // epilogue: per-wave bounce chunks of 16 rows x 64 cols through LDS.
  // eb regions live in buf0 bytes [0,9216) -- disjoint from buf1 (last-read
  // tile, bytes 16384+) and disjoint across waves: no barrier needed.
  u16* eb = (u16*)((char*)S + w * 2304);   // [16][72]
  u16* Cb  = Call  + (size_t)b * NN * NN;
  u16* CTb = CTall + (size_t)b * NN * NN;
  int erow = l >> 2, ec0 = (l & 3) * 16;
  #pragma unroll
  for (int mt = 0; mt < 4; mt++) {
    __asm__ volatile("s_waitcnt lgkmcnt(0)" ::: "memory");  // prev chunk reads done
    #pragma unroll
    for (int nt = 0; nt < 4; nt++)
      #pragma unroll
      for (int r = 0; r < 4; r++)
        eb[(quad * 4 + r) * 72 + nt * 16 + l16] = f2bf(acc[mt][nt][r]);
    __asm__ volatile("s_waitcnt lgkmcnt(0)" ::: "memory");  // writes visible
    int R0 = bRow + wm + mt * 16;
    if (writeC) {
      uint4 x0 = *(const uint4*)(eb + erow * 72 + ec0);
      uint4 x1 = *(const uint4*)(eb + erow * 72 + ec0 + 8);
      uint4* dst = (uint4*)(Cb + (size_t)(R0 + erow) * NN + bCol + wn + ec0);
      dst[0] = x0; dst[1] = x1;
    }
    if (writeT) {   // lane l = chunk column; write CT[col][R0..R0+15]
      unsigned pk[8];
      #pragma unroll
      for (int kk = 0; kk < 8; kk++)
        pk[kk] = (unsigned)eb[(2 * kk) * 72 + l] | ((unsigned)eb[(2 * kk + 1) * 72 + l] << 16);
      uint4* dst = (uint4*)(CTb + (size_t)(bCol + wn + l) * NN + R0);
      dst[0] = (uint4){pk[0], pk[1], pk[2], pk[3]};
      dst[1] = (uint4){pk[4], pk[5], pk[6], pk[7]};
    }
  }
}

// ---- K4: diag(P^5,6,7) via row-dots against P^4T ---------------------------
// diag(X * P^4)_i = sum_j X[i][j] * P4T[i][j]; one wave per row.
__global__ __launch_bounds__(256) void k_rowdot(const u16* __restrict__ X1,  // P
                                                const u16* __restrict__ X2,  // P^2
                                                const u16* __restrict__ X3,  // P^3
                                                const u16* __restrict__ YT,  // P^4T
                                                float* __restrict__ out) {
  int gw = blockIdx.x * 4 + (threadIdx.x >> 6);
  int l  = threadIdx.x & 63;
  size_t off = (size_t)gw * NN + l * 4;

  uint2 ya = *(const uint2*)(YT + off);
  uint2 xa = *(const uint2*)(X1 + off);
  uint2 xb = *(const uint2*)(X2 + off);
  uint2 xc = *(const uint2*)(X3 + off);
  float y0 = bf2f((u16)(ya.x & 0xffff)), y1 = bf2f((u16)(ya.x >> 16));
  float y2 = bf2f((u16)(ya.y & 0xffff)), y3 = bf2f((u16)(ya.y >> 16));

  float sa = bf2f((u16)(xa.x & 0xffff)) * y0 + bf2f((u16)(xa.x >> 16)) * y1
           + bf2f((u16)(xa.y & 0xffff)) * y2 + bf2f((u16)(xa.y >> 16)) * y3;
  float sb = bf2f((u16)(xb.x & 0xffff)) * y0 + bf2f((u16)(xb.x >> 16)) * y1
           + bf2f((u16)(xb.y & 0xffff)) * y2 + bf2f((u16)(xb.y >> 16)) * y3;
  float sc = bf2f((u16)(xc.x & 0xffff)) * y0 + bf2f((u16)(xc.x >> 16)) * y1
           + bf2f((u16)(xc.y & 0xffff)) * y2 + bf2f((u16)(xc.y >> 16)) * y3;
  #pragma unroll
  for (int o = 32; o; o >>= 1) {
    sa += __shfl_xor(sa, o);
    sb += __shfl_xor(sb, o);
    sc += __shfl_xor(sc, o);
  }
  if (l == 0) {
    size_t o = (size_t)gw * WL;
    out[o + 5] = sa;   // diag(P^5) = rowdot(P,   P^4T)
    out[o + 6] = sb;   // diag(P^6) = rowdot(P^2, P^4T)
    out[o + 7] = sc;   // diag(P^7) = rowdot(P^3, P^4T)
  }
}

extern "C" void kernel_launch(void* const* d_in, const int* in_sizes, int n_in,
                              void* d_out, int out_size, void* d_ws, size_t ws_size,
                              hipStream_t stream) {
  const float* A = (const float*)d_in[0];
  float* out = (float*)d_out;
  const size_t M3 = (size_t)BN * NN * NN;   // 32 MB per bf16 buffer
  u16* b0 = (u16*)d_ws;      // P
  u16* b1 = b0 + M3;         // P^T
  u16* b2 = b1 + M3;         // P^2
  u16* b3 = b2 + M3;         // P^3
  u16* b4 = b3 + M3;         // P^4T   (160 MB d_ws total)

  k_prep<<<BN * NN / 4, 256, 0, stream>>>(A, b0, out);                       // cols 0,1
  k_transpose<<<dim3(16, BN), 256, 0, stream>>>(b0, b1);                     // PT
  k_gemm<<<dim3(4, BN), 256, 0, stream>>>(b0, b1, b2, b2, out, 2, 1, 0);     // P2, col 2
  k_gemm<<<dim3(4, BN), 256, 0, stream>>>(b2, b1, b3, b3, out, 3, 1, 0);     // P3, col 3
  k_gemm<<<dim3(4, BN), 256, 0, stream>>>(b3, b1, b4, b4, out, 4, 0, 1);     // P4T, col 4
  k_rowdot<<<BN * NN / 4, 256, 0, stream>>>(b0, b2, b3, b4, out);            // cols 5,6,7
}